// Round 2
// 215.576 us; speedup vs baseline: 1.0749x; 1.0749x over previous
//
#include <hip/hip_runtime.h>

// (32, 3, 384, 640) fp32 in, (32, 1, 384, 640) fp32 out.
// v3: double-buffered channel pipeline with async global->LDS staging,
// staging made EXEC-UNIFORM (v2's failure: global_load_lds under divergent
// guards shifts the wave-uniform-base+lane*16 LDS destination).
//   - every global_load_lds runs with all 64 lanes active: tail groups clamp
//     the *global* source index (LDS dest stays lane-linear, lands in a pad),
//     edge columns clamp gc into [0, WW-4].
//   - reflection handled on the READ side: only LDS col 3 (bx==0, tx==0) and
//     col 132 (bx==4, tx==31) ever need reflected data; substitute the index
//     (reflect(-1)=1 -> col 5, reflect(640)=638 -> col 130). No divergence.
//   - single-pass vertical window: 4 LDS row reads per channel, shared rows'
//     x^2/y^2/xy computed once.
// LDS 2 * 5120 floats = 40960 B -> exactly 4 blocks/CU (16 waves/CU).
#define BATCH 32
#define CHAN  3
#define HH    384
#define WW    640
#define HW    (HH * WW)

#define OTW 128              // output tile width
#define OTH 16               // output tile height
#define LW  136              // LDS row width (cols colbase .. colbase+135)
#define LH  18               // LDS rows (h0-1 .. h0+16)
#define LPLANE  (LH * LW)    // 2448 floats per tensor plane
#define LFLOATS (2 * LPLANE) // 4896 floats of real data per channel buffer
#define LPAD    5120         // padded buffer size (1280 groups * 4 floats)
#define NGRP (LH * 34)       // 612 float4 groups per plane
#define NG2  (2 * NGRP)      // 1224 real groups per channel (padded to 1280)

#define GLOBAL_AS const __attribute__((address_space(1)))
#define LDS_AS __attribute__((address_space(3)))

__device__ __forceinline__ int reflectH(int v) {
    if (v < 0) v = -v;
    if (v >= HH) v = 2 * HH - 2 - v;
    return v;
}

// Stage one channel (x plane then y plane) into dst[0..LPAD).
// EXEC-UNIFORM: no lane ever skips the global_load_lds. LDS address is
// 16*g bytes, lane-linear in g (g = tid + 256k), satisfying the
// wave-uniform-base + lane*16 destination rule with a stable base.
__device__ __forceinline__ void stage_channel(const float* __restrict__ xp,
                                              const float* __restrict__ yp,
                                              float* dst,
                                              int tid, int colbase, int h0) {
#pragma unroll
    for (int k = 0; k < 5; k++) {
        const int g  = tid + 256 * k;
        const int gcl = (g < NG2) ? g : (NG2 - 1);    // clamp SOURCE index only
        const int t  = (gcl >= NGRP) ? 1 : 0;
        const int gg = gcl - t * NGRP;
        const int r  = (int)((unsigned)gg / 34u);
        const int q  = gg - r * 34;
        const float* __restrict__ pl = t ? yp : xp;
        const float* __restrict__ rowp = pl + (size_t)reflectH(h0 - 1 + r) * WW;
        int gc = colbase + 4 * q;
        gc = (gc < 0) ? 0 : gc;
        gc = (gc > WW - 4) ? (WW - 4) : gc;           // clamp SOURCE col only
        __builtin_amdgcn_global_load_lds(
            (GLOBAL_AS void*)(rowp + gc),
            (LDS_AS void*)(dst + 4 * g),              // dest stays lane-linear
            16, 0, 0);
    }
}

// One channel's contribution to acc[2][4] from a staged buffer.
// Single pass over the 4 input rows; two running 3-row window accumulators.
// jm/jp are the (possibly edge-substituted) left/right scalar column indices.
__device__ __forceinline__ void compute_channel(const float* __restrict__ buf,
                                                int ty, int jc, int jm, int jp,
                                                float (&acc)[2][4]) {
    const float inv9  = 1.0f / 9.0f;
    const float C1v   = 6.5025f;
    const float C2v   = 58.5225f;
    const float wssim = 0.5f * 0.85f / 3.0f;
    const float wl1   = 0.15f / 3.0f;

    const float* __restrict__ lx0 = buf;
    const float* __restrict__ ly0 = buf + LPLANE;
    const int lr = 2 * ty;

    float a0x[6], a0y[6], a0s[6], a0p[6];   // window rows lr..lr+2
    float a1x[6], a1y[6], a1s[6], a1p[6];   // window rows lr+1..lr+3
    float dab0[4], dab1[4];

#pragma unroll
    for (int r = 0; r < 4; r++) {
        const float* __restrict__ px = lx0 + (lr + r) * LW;
        const float* __restrict__ py = ly0 + (lr + r) * LW;
        float4 xm = *(const float4*)(px + jc);   // 16B-aligned ds_read_b128
        float4 ym = *(const float4*)(py + jc);
        float x[6], y[6];
        x[0] = px[jm]; x[1] = xm.x; x[2] = xm.y; x[3] = xm.z; x[4] = xm.w; x[5] = px[jp];
        y[0] = py[jm]; y[1] = ym.x; y[2] = ym.y; y[3] = ym.z; y[4] = ym.w; y[5] = py[jp];
#pragma unroll
        for (int i = 0; i < 6; i++) {
            float ss = fmaf(x[i], x[i], y[i] * y[i]);
            float pp = x[i] * y[i];
            if (r == 0) {
                a0x[i] = x[i]; a0y[i] = y[i]; a0s[i] = ss; a0p[i] = pp;
            } else if (r == 1) {
                a0x[i] += x[i]; a0y[i] += y[i]; a0s[i] += ss; a0p[i] += pp;
                a1x[i] = x[i];  a1y[i] = y[i];  a1s[i] = ss;  a1p[i] = pp;
            } else if (r == 2) {
                a0x[i] += x[i]; a0y[i] += y[i]; a0s[i] += ss; a0p[i] += pp;
                a1x[i] += x[i]; a1y[i] += y[i]; a1s[i] += ss; a1p[i] += pp;
            } else {
                a1x[i] += x[i]; a1y[i] += y[i]; a1s[i] += ss; a1p[i] += pp;
            }
        }
        if (r == 1) {
#pragma unroll
            for (int k = 0; k < 4; k++) dab0[k] = fabsf(x[k + 1] - y[k + 1]);
        }
        if (r == 2) {
#pragma unroll
            for (int k = 0; k < 4; k++) dab1[k] = fabsf(x[k + 1] - y[k + 1]);
        }
    }

#pragma unroll
    for (int k = 0; k < 4; k++) {
        float Sx  = a0x[k] + a0x[k + 1] + a0x[k + 2];
        float Sy  = a0y[k] + a0y[k + 1] + a0y[k + 2];
        float Sss = a0s[k] + a0s[k + 1] + a0s[k + 2];
        float Sxy = a0p[k] + a0p[k + 1] + a0p[k + 2];
        float mux = Sx * inv9;
        float muy = Sy * inv9;
        float mm  = mux * muy;
        float sigsum = fmaf(Sss, inv9, -(mux + muy));   // faithful: -mu, not -mu^2
        float sigxy  = fmaf(Sxy, inv9, -mm);
        float num = fmaf(2.0f, mm, C1v) * fmaf(2.0f, sigxy, C2v);
        float den = fmaf(muy, muy, fmaf(mux, mux, C1v)) * (sigsum + C2v);
        float q   = num * __builtin_amdgcn_rcpf(den);
        float ns  = fmaf(q, -0.5f, 0.5f);
        ns = fminf(fmaxf(ns, 0.0f), 1.0f);
        acc[0][k] = fmaf(wssim, ns, fmaf(wl1, dab0[k], acc[0][k]));
    }
#pragma unroll
    for (int k = 0; k < 4; k++) {
        float Sx  = a1x[k] + a1x[k + 1] + a1x[k + 2];
        float Sy  = a1y[k] + a1y[k + 1] + a1y[k + 2];
        float Sss = a1s[k] + a1s[k + 1] + a1s[k + 2];
        float Sxy = a1p[k] + a1p[k + 1] + a1p[k + 2];
        float mux = Sx * inv9;
        float muy = Sy * inv9;
        float mm  = mux * muy;
        float sigsum = fmaf(Sss, inv9, -(mux + muy));
        float sigxy  = fmaf(Sxy, inv9, -mm);
        float num = fmaf(2.0f, mm, C1v) * fmaf(2.0f, sigxy, C2v);
        float den = fmaf(muy, muy, fmaf(mux, mux, C1v)) * (sigsum + C2v);
        float q   = num * __builtin_amdgcn_rcpf(den);
        float ns  = fmaf(q, -0.5f, 0.5f);
        ns = fminf(fmaxf(ns, 0.0f), 1.0f);
        acc[1][k] = fmaf(wssim, ns, fmaf(wl1, dab1[k], acc[1][k]));
    }
}

__global__ __launch_bounds__(256, 4)
void ssim_l1_kernel(const float* __restrict__ src,
                    const float* __restrict__ tgt,
                    float* __restrict__ out) {
    __shared__ float lds[2 * LPAD];      // 40960 B -> 4 blocks/CU exactly

    const int tx  = threadIdx.x;         // 0..31
    const int ty  = threadIdx.y;         // 0..7
    const int tid = ty * 32 + tx;
    const int bx = blockIdx.x, by = blockIdx.y, b = blockIdx.z;

    const int colbase = bx * OTW - 4;    // 16B-aligned global col of LDS col 0
    const int h0 = by * OTH;
    const int jc = 4 * tx + 4;           // LDS col of this thread's first out px

    // Edge reflection via read-index substitution (see header comment).
    int jm = jc - 1, jp = jc + 4;
    if (bx == 0 && tx == 0)            jm = jc + 1;   // col 3 -> col 5
    if (bx == WW / OTW - 1 && tx == 31) jp = jc + 2;  // col 132 -> col 130

    const float* __restrict__ xb = src + (size_t)b * CHAN * HW;
    const float* __restrict__ yb = tgt + (size_t)b * CHAN * HW;

    float acc[2][4] = {{0.f, 0.f, 0.f, 0.f}, {0.f, 0.f, 0.f, 0.f}};

    // ---- software pipeline: stage(c+1) async || compute(c) ----
    stage_channel(xb + 0 * HW, yb + 0 * HW, &lds[0],    tid, colbase, h0);
    asm volatile("s_waitcnt vmcnt(0)" ::: "memory");
    __syncthreads();                                   // B1: buf0 ready

    stage_channel(xb + 1 * HW, yb + 1 * HW, &lds[LPAD], tid, colbase, h0);
    compute_channel(&lds[0], ty, jc, jm, jp, acc);     // ch0 while ch1 streams
    asm volatile("s_waitcnt vmcnt(0)" ::: "memory");
    __syncthreads();                                   // B2: buf1 ready, buf0 free

    stage_channel(xb + 2 * HW, yb + 2 * HW, &lds[0],    tid, colbase, h0);
    compute_channel(&lds[LPAD], ty, jc, jm, jp, acc);  // ch1 while ch2 streams
    asm volatile("s_waitcnt vmcnt(0)" ::: "memory");
    __syncthreads();                                   // B3: buf0 ready

    compute_channel(&lds[0], ty, jc, jm, jp, acc);     // ch2

#pragma unroll
    for (int rr = 0; rr < 2; rr++) {
        const int oh = h0 + 2 * ty + rr;
        *(float4*)(out + ((size_t)b * HH + oh) * WW + bx * OTW + 4 * tx) =
            make_float4(acc[rr][0], acc[rr][1], acc[rr][2], acc[rr][3]);
    }
}

extern "C" void kernel_launch(void* const* d_in, const int* in_sizes, int n_in,
                              void* d_out, int out_size, void* d_ws, size_t ws_size,
                              hipStream_t stream) {
    const float* src = (const float*)d_in[0];   // 'output'
    const float* tgt = (const float*)d_in[1];   // 'target'
    float* out = (float*)d_out;

    dim3 grid(WW / OTW, HH / OTH, BATCH);       // (5, 24, 32) = 3840 blocks
    dim3 block(32, 8);
    ssim_l1_kernel<<<grid, block, 0, stream>>>(src, tgt, out);
}